// Round 14
// baseline (2073.868 us; speedup 1.0000x reference)
//
#include <hip/hip_runtime.h>
#include <hip/hip_fp16.h>
#include <math.h>

#define D 512
#define NNODES 10000
#define NEDGES 80000
#define LAYERS 5
#define EPS 1e-5f
#define PPAN 625   // edge M-panels at BM=128 (CMAX producer)

typedef _Float16 f16x8 __attribute__((ext_vector_type(8)));
typedef float f32x4 __attribute__((ext_vector_type(4)));

// ---------- fp16 helpers ----------
__device__ inline unsigned short f2h(float x) { return __half_as_ushort(__float2half(x)); }
__device__ inline float h2f(unsigned short u) { return __half2float(__ushort_as_half(u)); }
__device__ inline uint4 pack8(const unsigned short* v) {
  uint4 r;
  r.x = (unsigned)v[0] | ((unsigned)v[1] << 16);
  r.y = (unsigned)v[2] | ((unsigned)v[3] << 16);
  r.z = (unsigned)v[4] | ((unsigned)v[5] << 16);
  r.w = (unsigned)v[6] | ((unsigned)v[7] << 16);
  return r;
}
__device__ inline void unpack8(uint4 v, unsigned short* o) {
  o[0] = v.x & 0xffff; o[1] = v.x >> 16;
  o[2] = v.y & 0xffff; o[3] = v.y >> 16;
  o[4] = v.z & 0xffff; o[5] = v.z >> 16;
  o[6] = v.w & 0xffff; o[7] = v.w >> 16;
}

__device__ inline void gload16(const void* g, void* l) {
  __builtin_amdgcn_global_load_lds((const __attribute__((address_space(1))) void*)g,
                                   (__attribute__((address_space(3))) void*)l, 16, 0, 0);
}

// ---------------------------------------------------------------------------
// A-format: fp16 rows; activation row = 1024 B, weight row = 2048 B. Within
// each 64 B K-block (4 octets of 16 B), octet o at slot (o&3)^((r>>1)&3).
// All EDGE-indexed arrays live in CSR (dst-sorted) order; eid maps
// csr-row -> original edge id (used only for the final f32 scatter).
// ---------------------------------------------------------------------------
__device__ inline int octA(int r, int o) {
  return ((o >> 2) << 6) + ((((o & 3) ^ ((r >> 1) & 3))) << 4);
}

// f32 [R][512] -> A-format fp16 (identity row order)
__global__ __launch_bounds__(256) void toF16_k(const float* __restrict__ src,
                                               char* __restrict__ dst, int nOct) {
  for (long long i = (long long)blockIdx.x * 256 + threadIdx.x; i < nOct;
       i += (long long)gridDim.x * 256) {
    int row = (int)(i >> 6), oct = (int)(i & 63);
    const float* s = src + (size_t)row * 512 + oct * 8;
    float4 x0 = *(const float4*)s, x1 = *(const float4*)(s + 4);
    float xs[8] = {x0.x, x0.y, x0.z, x0.w, x1.x, x1.y, x1.z, x1.w};
    unsigned short h[8];
#pragma unroll
    for (int j = 0; j < 8; j++) h[j] = f2h(xs[j]);
    *(uint4*)(dst + (size_t)row * 1024 + octA(row, oct)) = pack8(h);
  }
}

// permuted edge toF16: csr row i <- f32 row eid[i]
__global__ __launch_bounds__(256) void toF16perm_k(const float* __restrict__ src,
                                                   const int* __restrict__ eid,
                                                   char* __restrict__ dst) {
  for (long long i = (long long)blockIdx.x * 256 + threadIdx.x; i < (long long)NEDGES * 64;
       i += (long long)gridDim.x * 256) {
    int row = (int)(i >> 6), oct = (int)(i & 63);
    int orig = eid[row];
    const float* s = src + (size_t)orig * 512 + oct * 8;
    float4 x0 = *(const float4*)s, x1 = *(const float4*)(s + 4);
    float xs[8] = {x0.x, x0.y, x0.z, x0.w, x1.x, x1.y, x1.z, x1.w};
    unsigned short h[8];
#pragma unroll
    for (int j = 0; j < 8; j++) h[j] = f2h(xs[j]);
    *(uint4*)(dst + (size_t)row * 1024 + octA(row, oct)) = pack8(h);
  }
}

// permute src/dst into CSR order
__global__ __launch_bounds__(256) void permidx_k(const int* __restrict__ src,
                                                 const int* __restrict__ dst,
                                                 const int* __restrict__ eid,
                                                 int* __restrict__ srcp,
                                                 int* __restrict__ dstp) {
  int i = blockIdx.x * 256 + threadIdx.x;
  if (i < NEDGES) {
    int e = eid[i];
    srcp[i] = src[e];
    dstp[i] = dst[e];
  }
}

// weight prep: W[1024][512] f32 (15 mats) -> WT[n=512][k=1024] hi-only fp16
__global__ __launch_bounds__(256) void wprep_k(const float* __restrict__ Wa,
                                               const float* __restrict__ Wn,
                                               const float* __restrict__ We,
                                               char* __restrict__ WT) {
  __shared__ float tile[64][65];
  int mat = blockIdx.z;
  const float* W = (mat < 5) ? Wa + (size_t)mat * 1024 * 512
                 : (mat < 10) ? Wn + (size_t)(mat - 5) * 1024 * 512
                              : We + (size_t)(mat - 10) * 1024 * 512;
  char* out = WT + (size_t)mat * 512 * 2048;
  int n0 = blockIdx.x * 64, k0 = blockIdx.y * 64;
  int t = threadIdx.x;
  int ty = t >> 2, tx = t & 3;
  const float* wr = W + (size_t)(k0 + ty) * 512 + n0 + tx * 16;
  float4 v0 = *(const float4*)(wr + 0), v1 = *(const float4*)(wr + 4);
  float4 v2 = *(const float4*)(wr + 8), v3 = *(const float4*)(wr + 12);
  float vv[16] = {v0.x, v0.y, v0.z, v0.w, v1.x, v1.y, v1.z, v1.w,
                  v2.x, v2.y, v2.z, v2.w, v3.x, v3.y, v3.z, v3.w};
#pragma unroll
  for (int j = 0; j < 16; j++) tile[ty][tx * 16 + j] = vv[j];
  __syncthreads();
#pragma unroll
  for (int p = 0; p < 2; p++) {
    int chunk = t + p * 256;
    int n = chunk >> 3, cc = chunk & 7;
    float xs[8];
#pragma unroll
    for (int j = 0; j < 8; j++) xs[j] = tile[cc * 8 + j][n];
    unsigned short h[8];
#pragma unroll
    for (int j = 0; j < 8; j++) h[j] = f2h(xs[j]);
    int ng = n0 + n;
    int kc = (k0 >> 3) + cc;   // octet index 0..127
    *(uint4*)(out + (size_t)ng * 2048 + octA(ng, kc)) = pack8(h);
  }
}

// ---------------------------------------------------------------------------
// CSR build over dst (dst fixed across layers)
// ---------------------------------------------------------------------------
__global__ __launch_bounds__(256) void hist_k(const int* __restrict__ dst, int* __restrict__ cnt) {
  int e = blockIdx.x * 256 + threadIdx.x;
  if (e < NEDGES) atomicAdd(&cnt[dst[e]], 1);
}

__global__ __launch_bounds__(256) void scan_k(const int* __restrict__ cnt,
                                              int* __restrict__ off, int* __restrict__ cur) {
  __shared__ int part[256];
  const int CH = (NNODES + 255) / 256;
  int t = threadIdx.x;
  int s = 0;
  int l0 = t * CH;
  for (int i = 0; i < CH; i++) {
    int idx = l0 + i;
    if (idx < NNODES) s += cnt[idx];
  }
  part[t] = s;
  __syncthreads();
  if (t == 0) {
    int acc = 0;
    for (int i = 0; i < 256; i++) { int v = part[i]; part[i] = acc; acc += v; }
  }
  __syncthreads();
  int acc = part[t];
  for (int i = 0; i < CH; i++) {
    int idx = l0 + i;
    if (idx < NNODES) { off[idx] = acc; cur[idx] = acc; acc += cnt[idx]; }
  }
  if (t == 255) off[NNODES] = acc;
}

__global__ __launch_bounds__(256) void scatter_k(const int* __restrict__ dst,
                                                 int* __restrict__ cur, int* __restrict__ eid) {
  int e = blockIdx.x * 256 + threadIdx.x;
  if (e < NEDGES) {
    int p = atomicAdd(&cur[dst[e]], 1);
    eid[p] = e;
  }
}

// ---------------------------------------------------------------------------
// GEMM body: Y[R][512] = X@W, fp16 x fp16-hi. 3-buffer ring, depth-2
// prefetch, counted vmcnt + raw s_barrier, setprio. BM = 128 or 256.
// ---------------------------------------------------------------------------
template<int KT, bool ACT, bool OUT_I, bool CMAX, int BM>
__device__ __forceinline__ void gemm_body(char* smem,
                                          const char* __restrict__ X1,
                                          const char* __restrict__ X2,
                                          const char* __restrict__ BW, int cb0,
                                          void* __restrict__ Yout, int R,
                                          int flat, int total,
                                          const int* __restrict__ srcI,
                                          const int* __restrict__ dstI,
                                          const char* __restrict__ NaH,
                                          float* __restrict__ part_p,
                                          float* __restrict__ part_r,
                                          const int* __restrict__ rowMap) {
  constexpr int T = BM * 2;
  constexpr int BUF = (BM == 256) ? 24576 : 16384;
  constexpr int BOFF = (BM == 256) ? 16384 : 8192;
  constexpr int NH = BM / 64;
  constexpr int G = T / 32;
  const int tid = threadIdx.x;
  const int lane = tid & 63, wv = tid >> 6;
  const int NT = KT / 32;
  // bijective XCD chunking within role
  int xcd = flat & 7, idx = flat >> 3;
  int q = total >> 3, rem = total & 7;
  int base = xcd * q + (xcd < rem ? xcd : rem);
  int f2 = base + idx;
  const int bn0 = (f2 & 3) * 128, bm0 = (f2 >> 2) * BM;
  const int r16 = lane & 15, g = lane >> 4;
  const int mo = (wv >> 1) * 64, no = (wv & 1) * 64;
  const int lr16 = lane >> 2, ls16 = (lane & 3) * 16;
  f32x4 acc[4][4];
#pragma unroll
  for (int i = 0; i < 4; i++)
#pragma unroll
    for (int j = 0; j < 4; j++) acc[i][j] = (f32x4){0.f, 0.f, 0.f, 0.f};

  int offA[4], offB[4];
#pragma unroll
  for (int mi = 0; mi < 4; mi++) {
    int row = mo + mi * 16 + r16;
    offA[mi] = row * 64 + ((g ^ ((row >> 1) & 3)) << 4);
  }
#pragma unroll
  for (int ni = 0; ni < 4; ni++) {
    int row = no + ni * 16 + r16;
    offB[ni] = BOFF + row * 64 + ((g ^ ((row >> 1) & 3)) << 4);
  }

  const char* pA0;
  const char* pA1;
  const char* pB0;
  const char* pB1;
  {
    int g0 = bm0 + wv * 16 + lr16; if (g0 > R - 1) g0 = R - 1;
    int g1 = bm0 + (BM / 2) + wv * 16 + lr16; if (g1 > R - 1) g1 = R - 1;
    pA0 = X1 + (size_t)g0 * 1024 + ls16;
    pA1 = X1 + (size_t)g1 * 1024 + ls16;
    int n0r = bn0 + wv * 16 + lr16;
    pB0 = BW + (size_t)n0r * 2048 + cb0 * 16 + ls16;
    if (BM == 128) {
      int n1r = bn0 + (4 + wv) * 16 + lr16;
      pB1 = BW + (size_t)n1r * 2048 + cb0 * 16 + ls16;
    } else {
      pB1 = pB0;
    }
  }

  int us = 0;
#define STAGE()                                                 \
  {                                                             \
    char* sb = smem + (us % 3) * BUF;                           \
    gload16(pA0, sb + wv * 1024);                               \
    gload16(pA1, sb + ((BM / 32) + wv) * 1024);                 \
    gload16(pB0, sb + BOFF + wv * 1024);                        \
    if (BM == 128) gload16(pB1, sb + BOFF + (4 + wv) * 1024);   \
    pA0 += 64; pA1 += 64; pB0 += 64;                            \
    if (BM == 128) pB1 += 64;                                   \
    us++;                                                       \
  }

  STAGE();
  STAGE();
  for (int t = 0; t < NT; ++t) {
    if (t + 1 < NT) {
      if (BM == 128) asm volatile("s_waitcnt vmcnt(4)" ::: "memory");
      else           asm volatile("s_waitcnt vmcnt(3)" ::: "memory");
    } else {
      asm volatile("s_waitcnt vmcnt(0)" ::: "memory");
    }
    __builtin_amdgcn_s_barrier();
    if (us < NT) {
      if (KT == 1024 && us == 16) {
        int g0 = bm0 + wv * 16 + lr16; if (g0 > R - 1) g0 = R - 1;
        int g1 = bm0 + (BM / 2) + wv * 16 + lr16; if (g1 > R - 1) g1 = R - 1;
        pA0 = X2 + (size_t)g0 * 1024 + ls16;
        pA1 = X2 + (size_t)g1 * 1024 + ls16;
      }
      STAGE();
    }
    const char* As = smem + (t % 3) * BUF;
    f16x8 a[4], b[4];
#pragma unroll
    for (int mi = 0; mi < 4; mi++) a[mi] = *(const f16x8*)(As + offA[mi]);
#pragma unroll
    for (int ni = 0; ni < 4; ni++) b[ni] = *(const f16x8*)(As + offB[ni]);
    __builtin_amdgcn_s_setprio(1);
#pragma unroll
    for (int mi = 0; mi < 4; mi++)
#pragma unroll
      for (int ni = 0; ni < 4; ni++)
        acc[mi][ni] = __builtin_amdgcn_mfma_f32_16x16x32_f16(a[mi], b[ni], acc[mi][ni], 0, 0, 0);
    __builtin_amdgcn_s_setprio(0);
  }
#undef STAGE

  if (!OUT_I) {
    float* Y = (float*)Yout;
#pragma unroll
    for (int mi = 0; mi < 4; mi++)
#pragma unroll
      for (int j = 0; j < 4; j++) {
        int row = bm0 + mo + mi * 16 + g * 4 + j;
        if (row < R) {
          int orow = rowMap ? rowMap[row] : row;
#pragma unroll
          for (int ni = 0; ni < 4; ni++) {
            float v = acc[mi][ni][j];
            if (ACT) v = (v >= 0.f) ? v : 0.01f * v;
            Y[(size_t)orow * 512 + bn0 + no + ni * 16 + r16] = v;
          }
        }
      }
  } else {
    // Fused conflict-free epilogue: lane = one 16B chunk per iteration.
    float* stg = (float*)smem;
    const int hc = tid & 31;
    const int rg = tid >> 5;
    const int coct = (bn0 >> 3) + (hc >> 1);
    const int csub = (hc & 1) * 8;
    float4 mp4 = make_float4(-1e30f, -1e30f, -1e30f, -1e30f);
    float4 mr4 = mp4;
#pragma unroll
    for (int h = 0; h < NH; h++) {
      __syncthreads();
      if ((wv >> 1) == h) {
#pragma unroll
        for (int mi = 0; mi < 4; mi++)
#pragma unroll
          for (int j = 0; j < 4; j++) {
            int rl = mi * 16 + g * 4 + j;
#pragma unroll
            for (int ni = 0; ni < 4; ni++) {
              float v = acc[mi][ni][j];
              if (ACT) v = (v >= 0.f) ? v : 0.01f * v;
              stg[rl * 128 + no + ni * 16 + r16] = v;
            }
          }
      }
      __syncthreads();
#pragma unroll
      for (int qq = 0; qq < 2048 / T; qq++) {
        int rl = rg + qq * G;
        int grow = bm0 + h * 64 + rl;
        if (grow < R) {
          float4 v = *(const float4*)&stg[rl * 128 + hc * 4];
          unsigned short h0 = f2h(v.x), h1 = f2h(v.y), h2 = f2h(v.z), h3 = f2h(v.w);
          uint2 pk;
          pk.x = (unsigned)h0 | ((unsigned)h1 << 16);
          pk.y = (unsigned)h2 | ((unsigned)h3 << 16);
          int oct = (bn0 >> 3) + (hc >> 1);
          *(uint2*)((char*)Yout + (size_t)grow * 1024 + octA(grow, oct) + (hc & 1) * 8) = pk;
          if (CMAX) {
            int d = dstI[grow], s = srcI[grow];
            float qx = h2f(h0), qy = h2f(h1), qz = h2f(h2), qw = h2f(h3);
            uint2 hd = *(const uint2*)(NaH + (size_t)d * 1024 + octA(d, coct) + csub);
            uint2 hs = *(const uint2*)(NaH + (size_t)s * 1024 + octA(s, coct) + csub);
            mp4.x = fmaxf(mp4.x, qx + h2f(hd.x & 0xffff));
            mp4.y = fmaxf(mp4.y, qy + h2f(hd.x >> 16));
            mp4.z = fmaxf(mp4.z, qz + h2f(hd.y & 0xffff));
            mp4.w = fmaxf(mp4.w, qw + h2f(hd.y >> 16));
            mr4.x = fmaxf(mr4.x, qx + h2f(hs.x & 0xffff));
            mr4.y = fmaxf(mr4.y, qy + h2f(hs.x >> 16));
            mr4.z = fmaxf(mr4.z, qz + h2f(hs.y & 0xffff));
            mr4.w = fmaxf(mr4.w, qw + h2f(hs.y >> 16));
          }
        }
      }
    }
    if (CMAX) {
      __syncthreads();
      float* red = (float*)smem;
      *(float4*)&red[rg * 128 + hc * 4] = mp4;
      *(float4*)&red[G * 128 + rg * 128 + hc * 4] = mr4;
      __syncthreads();
      if (tid < 128) {
        float vp = -1e30f, vr = -1e30f;
#pragma unroll
        for (int gi = 0; gi < G; gi++) {
          vp = fmaxf(vp, red[gi * 128 + tid]);
          vr = fmaxf(vr, red[G * 128 + gi * 128 + tid]);
        }
        int panel = f2 >> 2;
        part_p[(size_t)panel * 512 + bn0 + tid] = vp;
        part_r[(size_t)panel * 512 + bn0 + tid] = vr;
      }
    }
  }
}

// standalone GEMM kernel (NaH producer / Ea+CMAX producer)
template<int KT, bool ACT, bool OUT_I, bool CMAX, int BM>
__global__ __launch_bounds__(BM * 2) void gemmI(const char* __restrict__ X1,
                                                const char* __restrict__ X2,
                                                const char* __restrict__ BW, int cb0,
                                                void* __restrict__ Yout, int R,
                                                const int* __restrict__ srcI,
                                                const int* __restrict__ dstI,
                                                const char* __restrict__ NaH,
                                                float* __restrict__ part_p,
                                                float* __restrict__ part_r) {
  __shared__ char smem[3 * ((BM == 256) ? 24576 : 16384)];
  gemm_body<KT, ACT, OUT_I, CMAX, BM>(smem, X1, X2, BW, cb0, Yout, R,
                                      blockIdx.y * 4 + blockIdx.x, gridDim.y * 4,
                                      srcI, dstI, NaH, part_p, part_r, nullptr);
}

// merged node+edge update: y<313 -> edge (BM=256, 313 panels), else node (40)
template<bool OUT_I>
__global__ __launch_bounds__(512) void gemmB_k(const char* __restrict__ z2I,
                                               const char* __restrict__ nxCur,
                                               const char* __restrict__ WnT,
                                               const char* __restrict__ blendH,
                                               const char* __restrict__ exCur,
                                               const char* __restrict__ WeT,
                                               void* __restrict__ nodeOut,
                                               void* __restrict__ edgeOut,
                                               const int* __restrict__ rowMap) {
  __shared__ char smem[3 * 24576];
  if (blockIdx.y < 313) {
    gemm_body<1024, true, OUT_I, false, 256>(smem, blendH, exCur, WeT, 0, edgeOut, NEDGES,
                                             blockIdx.y * 4 + blockIdx.x, 313 * 4,
                                             nullptr, nullptr, nullptr, nullptr, nullptr,
                                             rowMap);
  } else {
    gemm_body<1024, true, OUT_I, false, 256>(smem, z2I, nxCur, WnT, 0, nodeOut, NNODES,
                                             (blockIdx.y - 313) * 4 + blockIdx.x, 40 * 4,
                                             nullptr, nullptr, nullptr, nullptr, nullptr,
                                             nullptr);
  }
}

// colmax reduce stage 1: PPAN rows -> 5 segment rows (1024 cols: [p|r])
__global__ __launch_bounds__(256) void colmax_red1_k(const float* __restrict__ part,
                                                     float* __restrict__ part2) {
  int bx = blockIdx.x;
  int seg = bx >> 2;
  int idx = (bx & 3) * 256 + threadIdx.x;
  int c = idx & 511;
  const float* P = part + (size_t)(idx >> 9) * (PPAN * 512) + c;
  int b0 = seg * 125, b1 = b0 + 125;
  float v = -1e30f;
#pragma unroll 1
  for (int b = b0; b < b1; b += 5) {
    float v0 = P[(size_t)(b + 0) * 512], v1 = P[(size_t)(b + 1) * 512];
    float v2 = P[(size_t)(b + 2) * 512], v3 = P[(size_t)(b + 3) * 512];
    float v4 = P[(size_t)(b + 4) * 512];
    v = fmaxf(v, fmaxf(fmaxf(v0, v1), fmaxf(fmaxf(v2, v3), v4)));
  }
  part2[(size_t)seg * 1024 + idx] = v;
}

// colmax reduce stage 2: 5 segment rows -> m = [mp[512] | mr[512]]
__global__ __launch_bounds__(256) void colmax_red2_k(const float* __restrict__ part2,
                                                     float* __restrict__ m) {
  int idx = blockIdx.x * 256 + threadIdx.x;
  float v = part2[idx];
#pragma unroll
  for (int s = 1; s < 5; s++) v = fmaxf(v, part2[(size_t)s * 1024 + idx]);
  m[idx] = v;
}

// ---------------------------------------------------------------------------
// aggblend (CSR-ordered edges): per node n (one wave), edges are rows
// off[n]..off[n+1]-1 -> EaH/exI/blendH streams are contiguous. Depth-2
// pipeline (3 slots). Only nxI[s]/NaH[s] remain gathers (L3-resident).
// ---------------------------------------------------------------------------
__global__ __launch_bounds__(256) void aggblend_k(const char* __restrict__ EaH,
                                                  const char* __restrict__ NaH,
                                                  const char* __restrict__ exI,
                                                  const char* __restrict__ nxI,
                                                  const int* __restrict__ srcp,
                                                  const int* __restrict__ off,
                                                  const float* __restrict__ mp,
                                                  const float* __restrict__ mr,
                                                  char* __restrict__ blendH,
                                                  char* __restrict__ z2I) {
  const int w = threadIdx.x >> 6, o = threadIdx.x & 63;
  int n = blockIdx.x * 4 + w;
  if (n >= NNODES) return;
  float m_p[8], m_r[8], nd[8], xd[8], z[8], z2[8];
#pragma unroll
  for (int j = 0; j < 8; j++) {
    m_p[j] = mp[o * 8 + j];
    m_r[j] = mr[o * 8 + j];
    z[j] = 0.f; z2[j] = 0.f;
  }
  {
    unsigned short hn[8], hx[8];
    unpack8(*(const uint4*)(NaH + (size_t)n * 1024 + octA(n, o)), hn);
    unpack8(*(const uint4*)(nxI + (size_t)n * 1024 + octA(n, o)), hx);
#pragma unroll
    for (int j = 0; j < 8; j++) { nd[j] = h2f(hn[j]); xd[j] = h2f(hx[j]); }
  }
  const int i0 = off[n], i1 = off[n + 1];
  const int cnt = i1 - i0;
  if (cnt > 0) {
#define LOADE(ii, e_, ea_, x_, nn_, sv_)                             \
    {                                                                \
      e_ = ii;                                                       \
      int s_ = srcp[e_];                                             \
      ea_ = *(const uint4*)(EaH + (size_t)e_ * 1024 + octA(e_, o));  \
      x_  = *(const uint4*)(exI + (size_t)e_ * 1024 + octA(e_, o));  \
      nn_ = *(const uint4*)(nxI + (size_t)s_ * 1024 + octA(s_, o));  \
      sv_ = *(const uint4*)(NaH + (size_t)s_ * 1024 + octA(s_, o));  \
    }
    int eA, eB;
    uint4 eaA, xA, nA, svA, eaB, xB, nB, svB;
    LOADE(i0, eA, eaA, xA, nA, svA);
    if (cnt > 1) {
      LOADE(i0 + 1, eB, eaB, xB, nB, svB);
    } else {
      eB = eA; eaB = eaA; xB = xA; nB = nA; svB = svA;
    }
    for (int i = i0; i < i1; ++i) {
      int eC = eB;
      uint4 eaC = eaB, xC = xB, nC = nB, svC = svB;
      if (i + 2 < i1) {
        LOADE(i + 2, eC, eaC, xC, nC, svC);
      }
      unsigned short eh[8], xh[8], sh[8], sn[8];
      unpack8(eaA, eh);
      unpack8(xA, xh);
      unpack8(nA, sh);
      unpack8(svA, sn);
      unsigned short bh[8];
#pragma unroll
      for (int j = 0; j < 8; j++) {
        float ev = h2f(eh[j]);
        float spv = ev + nd[j] - m_p[j];
        float srv = ev + h2f(sn[j]) - m_r[j];
        float ap = __expf(spv);
        float xe = h2f(xh[j]);
        z[j] += ap;
        z2[j] += ap * xe;
        float u = srv - spv;
        float evx = __expf(-fabsf(u));
        float wpos = 1.f / (1.f + evx);
        float wr = (u >= 0.f) ? wpos : 1.f - wpos;
        float xs_ = h2f(sh[j]);
        bh[j] = f2h(wr * xs_ + (1.f - wr) * xd[j]);
      }
      *(uint4*)(blendH + (size_t)eA * 1024 + octA(eA, o)) = pack8(bh);
      eA = eB; eaA = eaB; xA = xB; nA = nB; svA = svB;
      eB = eC; eaB = eaC; xB = xC; nB = nC; svB = svC;
    }
#undef LOADE
  }
  unsigned short zh[8];
#pragma unroll
  for (int j = 0; j < 8; j++) zh[j] = f2h(z2[j] / (z[j] + EPS));
  *(uint4*)(z2I + (size_t)n * 1024 + octA(n, o)) = pack8(zh);
}

// node_conf = nx @ Wnc ([512,55])
__global__ __launch_bounds__(256) void nodeconf_k(const float* __restrict__ nx,
                                                  const float* __restrict__ Wnc,
                                                  float* __restrict__ out) {
  int w = threadIdx.x >> 6, lane = threadIdx.x & 63;
  int n = blockIdx.x * 4 + w;
  const float* r = nx + (size_t)n * D;
  if (lane < 55) {
    float acc = 0.f;
    for (int k = 0; k < D; k++) acc = fmaf(r[k], Wnc[k * 55 + lane], acc);
    out[(size_t)n * 55 + lane] = acc;
  }
}

// edge_conf = ex @ Wec ([512,2]) — float4-vectorized
__global__ __launch_bounds__(256) void edgeconf_k(const float* __restrict__ ex,
                                                  const float* __restrict__ Wec,
                                                  float* __restrict__ out) {
  int w = threadIdx.x >> 6, lane = threadIdx.x & 63;
  int e = blockIdx.x * 4 + w;
  const float* r = ex + (size_t)e * D + lane * 8;
  float4 v0 = *(const float4*)r;
  float4 v1 = *(const float4*)(r + 4);
  const float* wp = Wec + lane * 16;
  float vv[8] = {v0.x, v0.y, v0.z, v0.w, v1.x, v1.y, v1.z, v1.w};
  float a0 = 0.f, a1 = 0.f;
#pragma unroll
  for (int j = 0; j < 8; j++) {
    a0 = fmaf(vv[j], wp[j * 2 + 0], a0);
    a1 = fmaf(vv[j], wp[j * 2 + 1], a1);
  }
#pragma unroll
  for (int off = 32; off; off >>= 1) {
    a0 += __shfl_down(a0, off);
    a1 += __shfl_down(a1, off);
  }
  if (lane == 0) { out[(size_t)e * 2 + 0] = a0; out[(size_t)e * 2 + 1] = a1; }
}

extern "C" void kernel_launch(void* const* d_in, const int* in_sizes, int n_in,
                              void* d_out, int out_size, void* d_ws, size_t ws_size,
                              hipStream_t stream) {
  const float* in_nx = (const float*)d_in[0];
  const float* in_ex = (const float*)d_in[1];
  const int* src = (const int*)d_in[2];
  const int* dst = (const int*)d_in[3];
  const float* Wa = (const float*)d_in[4];
  const float* Wn = (const float*)d_in[5];
  const float* We = (const float*)d_in[6];
  const float* Wnc = (const float*)d_in[7];
  const float* Wec = (const float*)d_in[8];

  float* out = (float*)d_out;
  float* o_nx = out;
  float* o_nc = o_nx + (size_t)NNODES * D;
  float* o_ex = o_nc + (size_t)NNODES * 55;
  float* o_ec = o_ex + (size_t)NEDGES * D;

  const size_t SZ_EH = (size_t)NEDGES * 1024;   // 80 MB fp16 edge rows
  const size_t SZ_NH = (size_t)NNODES * 1024;   // 10 MB fp16 node rows
  const size_t MATSZ = (size_t)512 * 2048;      // 1 MB per weight mat (hi-only)
  char* w = (char*)d_ws;
  char* EaH = w;                                // fp16 Ea (csr order)
  char* blendH = w + SZ_EH;                     // fp16 blend (csr order)
  char* exA = w + 2 * SZ_EH;                    // exI ping (csr order)
  char* nxA = w + 3 * SZ_EH;                    // nxI ping
  char* NaH = w + 3 * SZ_EH + SZ_NH;            // fp16 Na (A-format)
  char* z2I = w + 3 * SZ_EH + 2 * SZ_NH;
  float* mpf = (float*)(w + 3 * SZ_EH + 3 * SZ_NH);  // [mp|mr]
  char* WT = w + 3 * SZ_EH + 3 * SZ_NH + 8192;
  char* csr = WT + 15 * MATSZ;
  int* cnt = (int*)csr;
  int* offp = cnt + NNODES + 8;
  int* cur = offp + NNODES + 8;
  int* eid = cur + NNODES + 8;                  // csr-row -> orig edge
  int* srcp = eid + NEDGES;
  int* dstp = srcp + NEDGES;
  float* part_p = (float*)(dstp + NEDGES);      // PPAN*512
  float* part_r = part_p + PPAN * 512;
  float* part2 = part_r + PPAN * 512;           // 5*1024

  char* exB = (char*)o_ex;   // fp16 ping inside f32 output regions
  char* nxB = (char*)o_nx;

  // one-time prep
  wprep_k<<<dim3(8, 16, 15), 256, 0, stream>>>(Wa, Wn, We, WT);
  toF16_k<<<2048, 256, 0, stream>>>(in_nx, nxA, NNODES * 64);
  hipMemsetAsync(cnt, 0, NNODES * sizeof(int), stream);
  hist_k<<<(NEDGES + 255) / 256, 256, 0, stream>>>(dst, cnt);
  scan_k<<<1, 256, 0, stream>>>(cnt, offp, cur);
  scatter_k<<<(NEDGES + 255) / 256, 256, 0, stream>>>(dst, cur, eid);
  permidx_k<<<(NEDGES + 255) / 256, 256, 0, stream>>>(src, dst, eid, srcp, dstp);
  toF16perm_k<<<2048, 256, 0, stream>>>(in_ex, eid, exA);

  dim3 gE128(4, PPAN);                // (4, 625) BM=128 (Ea+CMAX)
  dim3 gN(4, (NNODES + 127) / 128);   // (4, 79)  BM=128
  dim3 gB(4, 353);                    // merged node+edge update, BM=256

  for (int l = 0; l < LAYERS; l++) {
    const char* WaT = WT + (size_t)l * MATSZ;
    const char* WnT = WT + (size_t)(5 + l) * MATSZ;
    const char* WeT = WT + (size_t)(10 + l) * MATSZ;
    char* exCur = (l & 1) ? exB : exA;
    char* exNxt = (l & 1) ? exA : exB;
    char* nxCur = (l & 1) ? nxB : nxA;
    char* nxNxt = (l & 1) ? nxA : nxB;

    // NaH = fp16(nx @ Wa_bot), then EaH = fp16(ex @ Wa_top) with fused colmax
    gemmI<512, false, true, false, 128><<<gN, 256, 0, stream>>>(
        nxCur, nullptr, WaT, 64, NaH, NNODES, nullptr, nullptr, nullptr, nullptr, nullptr);
    gemmI<512, false, true, true, 128><<<gE128, 256, 0, stream>>>(
        exCur, nullptr, WaT, 0, EaH, NEDGES, srcp, dstp, NaH, part_p, part_r);

    colmax_red1_k<<<20, 256, 0, stream>>>(part_p, part2);
    colmax_red2_k<<<4, 256, 0, stream>>>(part2, mpf);

    aggblend_k<<<(NNODES + 3) / 4, 256, 0, stream>>>(EaH, NaH, exCur, nxA == exCur ? nxA : ((l & 1) ? nxB : nxA), srcp,
                                                     offp, mpf, mpf + 512, blendH, z2I);

    // merged node+edge update
    if (l < 4)
      gemmB_k<true><<<gB, 512, 0, stream>>>(z2I, nxCur, WnT, blendH, exCur, WeT,
                                            nxNxt, exNxt, nullptr);
    else
      gemmB_k<false><<<gB, 512, 0, stream>>>(z2I, nxCur, WnT, blendH, exCur, WeT,
                                             o_nx, o_ex, eid);
  }

  nodeconf_k<<<NNODES / 4, 256, 0, stream>>>(o_nx, Wnc, o_nc);
  edgeconf_k<<<NEDGES / 4, 256, 0, stream>>>(o_ex, Wec, o_ec);
}

// Round 16
// 2055.348 us; speedup vs baseline: 1.0090x; 1.0090x over previous
//
#include <hip/hip_runtime.h>
#include <hip/hip_fp16.h>
#include <math.h>

#define D 512
#define NNODES 10000
#define NEDGES 80000
#define LAYERS 5
#define EPS 1e-5f
#define PPAN 625   // edge M-panels at BM=128 (CMAX producer)

typedef _Float16 f16x8 __attribute__((ext_vector_type(8)));
typedef float f32x4 __attribute__((ext_vector_type(4)));

// ---------- fp16 helpers ----------
__device__ inline unsigned short f2h(float x) { return __half_as_ushort(__float2half(x)); }
__device__ inline float h2f(unsigned short u) { return __half2float(__ushort_as_half(u)); }
__device__ inline uint4 pack8(const unsigned short* v) {
  uint4 r;
  r.x = (unsigned)v[0] | ((unsigned)v[1] << 16);
  r.y = (unsigned)v[2] | ((unsigned)v[3] << 16);
  r.z = (unsigned)v[4] | ((unsigned)v[5] << 16);
  r.w = (unsigned)v[6] | ((unsigned)v[7] << 16);
  return r;
}
__device__ inline void unpack8(uint4 v, unsigned short* o) {
  o[0] = v.x & 0xffff; o[1] = v.x >> 16;
  o[2] = v.y & 0xffff; o[3] = v.y >> 16;
  o[4] = v.z & 0xffff; o[5] = v.z >> 16;
  o[6] = v.w & 0xffff; o[7] = v.w >> 16;
}

__device__ inline void gload16(const void* g, void* l) {
  __builtin_amdgcn_global_load_lds((const __attribute__((address_space(1))) void*)g,
                                   (__attribute__((address_space(3))) void*)l, 16, 0, 0);
}

// ---------------------------------------------------------------------------
// A-format (activations AND hi-only weights): fp16 rows; activation row =
// 1024 B (K=512), weight row = 2048 B (K=1024). Within each 64 B K-block
// (4 octets of 16 B), octet o sits at slot (o&3)^((r>>1)&3).
// ---------------------------------------------------------------------------
__device__ inline int octA(int r, int o) {
  return ((o >> 2) << 6) + ((((o & 3) ^ ((r >> 1) & 3))) << 4);
}

// f32 [R][512] -> A-format fp16
__global__ __launch_bounds__(256) void toF16_k(const float* __restrict__ src,
                                               char* __restrict__ dst, int nOct) {
  for (long long i = (long long)blockIdx.x * 256 + threadIdx.x; i < nOct;
       i += (long long)gridDim.x * 256) {
    int row = (int)(i >> 6), oct = (int)(i & 63);
    const float* s = src + (size_t)row * 512 + oct * 8;
    float4 x0 = *(const float4*)s, x1 = *(const float4*)(s + 4);
    float xs[8] = {x0.x, x0.y, x0.z, x0.w, x1.x, x1.y, x1.z, x1.w};
    unsigned short h[8];
#pragma unroll
    for (int j = 0; j < 8; j++) h[j] = f2h(xs[j]);
    *(uint4*)(dst + (size_t)row * 1024 + octA(row, oct)) = pack8(h);
  }
}

// weight prep: W[1024][512] f32 (15 mats) -> WT[n=512][k=1024] hi-only fp16
__global__ __launch_bounds__(256) void wprep_k(const float* __restrict__ Wa,
                                               const float* __restrict__ Wn,
                                               const float* __restrict__ We,
                                               char* __restrict__ WT) {
  __shared__ float tile[64][65];
  int mat = blockIdx.z;
  const float* W = (mat < 5) ? Wa + (size_t)mat * 1024 * 512
                 : (mat < 10) ? Wn + (size_t)(mat - 5) * 1024 * 512
                              : We + (size_t)(mat - 10) * 1024 * 512;
  char* out = WT + (size_t)mat * 512 * 2048;
  int n0 = blockIdx.x * 64, k0 = blockIdx.y * 64;
  int t = threadIdx.x;
  int ty = t >> 2, tx = t & 3;
  const float* wr = W + (size_t)(k0 + ty) * 512 + n0 + tx * 16;
  float4 v0 = *(const float4*)(wr + 0), v1 = *(const float4*)(wr + 4);
  float4 v2 = *(const float4*)(wr + 8), v3 = *(const float4*)(wr + 12);
  float vv[16] = {v0.x, v0.y, v0.z, v0.w, v1.x, v1.y, v1.z, v1.w,
                  v2.x, v2.y, v2.z, v2.w, v3.x, v3.y, v3.z, v3.w};
#pragma unroll
  for (int j = 0; j < 16; j++) tile[ty][tx * 16 + j] = vv[j];
  __syncthreads();
#pragma unroll
  for (int p = 0; p < 2; p++) {
    int chunk = t + p * 256;
    int n = chunk >> 3, cc = chunk & 7;
    float xs[8];
#pragma unroll
    for (int j = 0; j < 8; j++) xs[j] = tile[cc * 8 + j][n];
    unsigned short h[8];
#pragma unroll
    for (int j = 0; j < 8; j++) h[j] = f2h(xs[j]);
    int ng = n0 + n;
    int kc = (k0 >> 3) + cc;   // octet index 0..127
    *(uint4*)(out + (size_t)ng * 2048 + octA(ng, kc)) = pack8(h);
  }
}

// ---------------------------------------------------------------------------
// CSR build over dst (dst fixed across layers)
// ---------------------------------------------------------------------------
__global__ __launch_bounds__(256) void hist_k(const int* __restrict__ dst, int* __restrict__ cnt) {
  int e = blockIdx.x * 256 + threadIdx.x;
  if (e < NEDGES) atomicAdd(&cnt[dst[e]], 1);
}

__global__ __launch_bounds__(256) void scan_k(const int* __restrict__ cnt,
                                              int* __restrict__ off, int* __restrict__ cur) {
  __shared__ int part[256];
  const int CH = (NNODES + 255) / 256;
  int t = threadIdx.x;
  int s = 0;
  int l0 = t * CH;
  for (int i = 0; i < CH; i++) {
    int idx = l0 + i;
    if (idx < NNODES) s += cnt[idx];
  }
  part[t] = s;
  __syncthreads();
  if (t == 0) {
    int acc = 0;
    for (int i = 0; i < 256; i++) { int v = part[i]; part[i] = acc; acc += v; }
  }
  __syncthreads();
  int acc = part[t];
  for (int i = 0; i < CH; i++) {
    int idx = l0 + i;
    if (idx < NNODES) { off[idx] = acc; cur[idx] = acc; acc += cnt[idx]; }
  }
  if (t == 255) off[NNODES] = acc;
}

__global__ __launch_bounds__(256) void scatter_k(const int* __restrict__ dst,
                                                 int* __restrict__ cur, int* __restrict__ eid) {
  int e = blockIdx.x * 256 + threadIdx.x;
  if (e < NEDGES) {
    int p = atomicAdd(&cur[dst[e]], 1);
    eid[p] = e;
  }
}

// ---------------------------------------------------------------------------
// gemmI (ring-3): BM=128 structure, used for NaH / Ea+CMAX / node updates.
// ---------------------------------------------------------------------------
template<int KT, bool ACT, bool OUT_I, bool CMAX, int BM>
__global__ __launch_bounds__(BM * 2) void gemmI(const char* __restrict__ X1,
                                                const char* __restrict__ X2,
                                                const char* __restrict__ BW, int cb0,
                                                void* __restrict__ Yout, int R,
                                                const int* __restrict__ srcI,
                                                const int* __restrict__ dstI,
                                                const char* __restrict__ NaH,
                                                float* __restrict__ part_p,
                                                float* __restrict__ part_r) {
  constexpr int T = BM * 2;
  constexpr int BUF = (BM == 256) ? 24576 : 16384;
  constexpr int BOFF = (BM == 256) ? 16384 : 8192;
  constexpr int NH = BM / 64;
  constexpr int G = T / 32;
  __shared__ char smem[3 * BUF];
  const int tid = threadIdx.x;
  const int lane = tid & 63, wv = tid >> 6;
  const int NT = KT / 32;
  int flat = blockIdx.y * 4 + blockIdx.x;
  int total = gridDim.y * 4;
  int xcd = flat & 7, idx = flat >> 3;
  int q = total >> 3, rem = total & 7;
  int base = xcd * q + (xcd < rem ? xcd : rem);
  int f2 = base + idx;
  const int bn0 = (f2 & 3) * 128, bm0 = (f2 >> 2) * BM;
  const int r16 = lane & 15, g = lane >> 4;
  const int mo = (wv >> 1) * 64, no = (wv & 1) * 64;
  const int lr16 = lane >> 2, ls16 = (lane & 3) * 16;
  f32x4 acc[4][4];
#pragma unroll
  for (int i = 0; i < 4; i++)
#pragma unroll
    for (int j = 0; j < 4; j++) acc[i][j] = (f32x4){0.f, 0.f, 0.f, 0.f};

  int offA[4], offB[4];
#pragma unroll
  for (int mi = 0; mi < 4; mi++) {
    int row = mo + mi * 16 + r16;
    offA[mi] = row * 64 + ((g ^ ((row >> 1) & 3)) << 4);
  }
#pragma unroll
  for (int ni = 0; ni < 4; ni++) {
    int row = no + ni * 16 + r16;
    offB[ni] = BOFF + row * 64 + ((g ^ ((row >> 1) & 3)) << 4);
  }

  const char* pA0;
  const char* pA1;
  const char* pB0;
  const char* pB1;
  {
    int g0 = bm0 + wv * 16 + lr16; if (g0 > R - 1) g0 = R - 1;
    int g1 = bm0 + (BM / 2) + wv * 16 + lr16; if (g1 > R - 1) g1 = R - 1;
    pA0 = X1 + (size_t)g0 * 1024 + ls16;
    pA1 = X1 + (size_t)g1 * 1024 + ls16;
    int n0r = bn0 + wv * 16 + lr16;
    pB0 = BW + (size_t)n0r * 2048 + cb0 * 16 + ls16;
    if (BM == 128) {
      int n1r = bn0 + (4 + wv) * 16 + lr16;
      pB1 = BW + (size_t)n1r * 2048 + cb0 * 16 + ls16;
    } else {
      pB1 = pB0;
    }
  }

  int us = 0;
#define STAGE()                                                 \
  {                                                             \
    char* sb = smem + (us % 3) * BUF;                           \
    gload16(pA0, sb + wv * 1024);                               \
    gload16(pA1, sb + ((BM / 32) + wv) * 1024);                 \
    gload16(pB0, sb + BOFF + wv * 1024);                        \
    if (BM == 128) gload16(pB1, sb + BOFF + (4 + wv) * 1024);   \
    pA0 += 64; pA1 += 64; pB0 += 64;                            \
    if (BM == 128) pB1 += 64;                                   \
    us++;                                                       \
  }

  STAGE();
  STAGE();
  for (int t = 0; t < NT; ++t) {
    if (t + 1 < NT) {
      if (BM == 128) asm volatile("s_waitcnt vmcnt(4)" ::: "memory");
      else           asm volatile("s_waitcnt vmcnt(3)" ::: "memory");
    } else {
      asm volatile("s_waitcnt vmcnt(0)" ::: "memory");
    }
    __builtin_amdgcn_s_barrier();
    if (us < NT) {
      if (KT == 1024 && us == 16) {
        int g0 = bm0 + wv * 16 + lr16; if (g0 > R - 1) g0 = R - 1;
        int g1 = bm0 + (BM / 2) + wv * 16 + lr16; if (g1 > R - 1) g1 = R - 1;
        pA0 = X2 + (size_t)g0 * 1024 + ls16;
        pA1 = X2 + (size_t)g1 * 1024 + ls16;
      }
      STAGE();
    }
    const char* As = smem + (t % 3) * BUF;
    f16x8 a[4], b[4];
#pragma unroll
    for (int mi = 0; mi < 4; mi++) a[mi] = *(const f16x8*)(As + offA[mi]);
#pragma unroll
    for (int ni = 0; ni < 4; ni++) b[ni] = *(const f16x8*)(As + offB[ni]);
    __builtin_amdgcn_s_setprio(1);
#pragma unroll
    for (int mi = 0; mi < 4; mi++)
#pragma unroll
      for (int ni = 0; ni < 4; ni++)
        acc[mi][ni] = __builtin_amdgcn_mfma_f32_16x16x32_f16(a[mi], b[ni], acc[mi][ni], 0, 0, 0);
    __builtin_amdgcn_s_setprio(0);
  }
#undef STAGE

  if (!OUT_I) {
    float* Y = (float*)Yout;
#pragma unroll
    for (int mi = 0; mi < 4; mi++)
#pragma unroll
      for (int j = 0; j < 4; j++) {
        int row = bm0 + mo + mi * 16 + g * 4 + j;
        if (row < R) {
#pragma unroll
          for (int ni = 0; ni < 4; ni++) {
            float v = acc[mi][ni][j];
            if (ACT) v = (v >= 0.f) ? v : 0.01f * v;
            Y[(size_t)row * 512 + bn0 + no + ni * 16 + r16] = v;
          }
        }
      }
  } else {
    float* stg = (float*)smem;
    const int hc = tid & 31;
    const int rg = tid >> 5;
    const int coct = (bn0 >> 3) + (hc >> 1);
    const int csub = (hc & 1) * 8;
    float4 mp4 = make_float4(-1e30f, -1e30f, -1e30f, -1e30f);
    float4 mr4 = mp4;
#pragma unroll
    for (int h = 0; h < NH; h++) {
      __syncthreads();
      if ((wv >> 1) == h) {
#pragma unroll
        for (int mi = 0; mi < 4; mi++)
#pragma unroll
          for (int j = 0; j < 4; j++) {
            int rl = mi * 16 + g * 4 + j;
#pragma unroll
            for (int ni = 0; ni < 4; ni++) {
              float v = acc[mi][ni][j];
              if (ACT) v = (v >= 0.f) ? v : 0.01f * v;
              stg[rl * 128 + no + ni * 16 + r16] = v;
            }
          }
      }
      __syncthreads();
#pragma unroll
      for (int qq = 0; qq < 2048 / T; qq++) {
        int rl = rg + qq * G;
        int grow = bm0 + h * 64 + rl;
        if (grow < R) {
          float4 v = *(const float4*)&stg[rl * 128 + hc * 4];
          unsigned short h0 = f2h(v.x), h1 = f2h(v.y), h2 = f2h(v.z), h3 = f2h(v.w);
          uint2 pk;
          pk.x = (unsigned)h0 | ((unsigned)h1 << 16);
          pk.y = (unsigned)h2 | ((unsigned)h3 << 16);
          int oct = (bn0 >> 3) + (hc >> 1);
          *(uint2*)((char*)Yout + (size_t)grow * 1024 + octA(grow, oct) + (hc & 1) * 8) = pk;
          if (CMAX) {
            int d = dstI[grow], s = srcI[grow];
            float qx = h2f(h0), qy = h2f(h1), qz = h2f(h2), qw = h2f(h3);
            uint2 hd = *(const uint2*)(NaH + (size_t)d * 1024 + octA(d, coct) + csub);
            uint2 hs = *(const uint2*)(NaH + (size_t)s * 1024 + octA(s, coct) + csub);
            mp4.x = fmaxf(mp4.x, qx + h2f(hd.x & 0xffff));
            mp4.y = fmaxf(mp4.y, qy + h2f(hd.x >> 16));
            mp4.z = fmaxf(mp4.z, qz + h2f(hd.y & 0xffff));
            mp4.w = fmaxf(mp4.w, qw + h2f(hd.y >> 16));
            mr4.x = fmaxf(mr4.x, qx + h2f(hs.x & 0xffff));
            mr4.y = fmaxf(mr4.y, qy + h2f(hs.x >> 16));
            mr4.z = fmaxf(mr4.z, qz + h2f(hs.y & 0xffff));
            mr4.w = fmaxf(mr4.w, qw + h2f(hs.y >> 16));
          }
        }
      }
    }
    if (CMAX) {
      __syncthreads();
      float* red = (float*)smem;
      *(float4*)&red[rg * 128 + hc * 4] = mp4;
      *(float4*)&red[G * 128 + rg * 128 + hc * 4] = mr4;
      __syncthreads();
      if (tid < 128) {
        float vp = -1e30f, vr = -1e30f;
#pragma unroll
        for (int gi = 0; gi < G; gi++) {
          vp = fmaxf(vp, red[gi * 128 + tid]);
          vr = fmaxf(vr, red[G * 128 + gi * 128 + tid]);
        }
        int panel = f2 >> 2;
        part_p[(size_t)panel * 512 + bn0 + tid] = vp;
        part_r[(size_t)panel * 512 + bn0 + tid] = vr;
      }
    }
  }
}

// ---------------------------------------------------------------------------
// gemm8_k: 8-phase 256x256 edge-update GEMM. Y = act(concat(X1,X2) @ BW).
// Per phase: ds_read quadrant frags; stage 1 quarter of tile T+1 (2 gloads);
// vmcnt(4); s_barrier; 16 MFMA (setprio); s_barrier.
// Prologue stages tile 0 fully then DRAINS vmcnt(0)+barrier (round-15 bug fix).
// ---------------------------------------------------------------------------
template<bool OUT_I>
__global__ __launch_bounds__(512) void gemm8_k(const char* __restrict__ X1,
                                               const char* __restrict__ X2,
                                               const char* __restrict__ BW,
                                               void* __restrict__ Yout) {
  __shared__ char smem[131072];
  const int R = NEDGES;
  const int tid = threadIdx.x;
  const int lane = tid & 63, wv = tid >> 6;
  const int wm = wv >> 2, wn = wv & 3;
  const int r16 = lane & 15, g = lane >> 4;
  // XCD swizzle over 626 blocks
  int flat = blockIdx.y * 2 + blockIdx.x;
  int total = 626;
  int xcd = flat & 7, idx = flat >> 3;
  int q8 = total >> 3, rem = total & 7;
  int base = xcd * q8 + (xcd < rem ? xcd : rem);
  int f2 = base + idx;
  const int bn0 = (f2 & 1) * 256, bm0 = (f2 >> 1) * 256;

  f32x4 acc[8][4];
#pragma unroll
  for (int i = 0; i < 8; i++)
#pragma unroll
    for (int j = 0; j < 4; j++) acc[i][j] = (f32x4){0.f, 0.f, 0.f, 0.f};

  const int slot = ((g ^ ((r16 >> 1) & 3)) << 4);
  const int baseA = (wm * 128 + r16) * 64 + slot;          // + fm*1024 + ks*16384
  const int baseB = 32768 + (wn * 64 + r16) * 64 + slot;   // + ni*1024 + ks*16384

  // staging: quarter q of tile Tn into buffer bb. q: 0=A-s0,1=B-s0,2=A-s1,3=B-s1
  const int srow = wv * 32 + (lane >> 2);   // + 16 for second gload
  const int sslot = (lane & 3) * 16;
#define STAGEQ(Tn, bb, qq)                                                     \
  {                                                                            \
    int s_ = (qq) >> 1;                                                        \
    char* ldsq = smem + (bb) * 65536 + (((qq) & 1) ? 32768 : 0) + s_ * 16384 + \
                 wv * 2048;                                                    \
    if (((qq) & 1) == 0) {                                                     \
      const char* xb; int tl;                                                  \
      if ((Tn) < 8) { xb = X1; tl = (Tn); } else { xb = X2; tl = (Tn) - 8; }   \
      int r0 = bm0 + srow; if (r0 > R - 1) r0 = R - 1;                         \
      int r1 = bm0 + srow + 16; if (r1 > R - 1) r1 = R - 1;                    \
      gload16(xb + (size_t)r0 * 1024 + tl * 128 + s_ * 64 + sslot, ldsq);      \
      gload16(xb + (size_t)r1 * 1024 + tl * 128 + s_ * 64 + sslot, ldsq + 1024);\
    } else {                                                                   \
      int r0 = bn0 + srow;                                                     \
      int r1 = r0 + 16;                                                        \
      gload16(BW + (size_t)r0 * 2048 + (Tn) * 128 + s_ * 64 + sslot, ldsq);    \
      gload16(BW + (size_t)r1 * 2048 + (Tn) * 128 + s_ * 64 + sslot, ldsq + 1024);\
    }                                                                          \
  }

  // prologue: tile 0 fully staged into buf 0, then DRAIN before first ds_read
  STAGEQ(0, 0, 0); STAGEQ(0, 0, 1); STAGEQ(0, 0, 2); STAGEQ(0, 0, 3);
  asm volatile("s_waitcnt vmcnt(0)" ::: "memory");
  __builtin_amdgcn_s_barrier();

  f16x8 b[4];
  for (int T = 0; T < 16; ++T) {
    const int buf = T & 1;
    const char* Ab = smem + buf * 65536;
#pragma unroll
    for (int q = 0; q < 4; ++q) {
      const int mh = q & 1, ks = q >> 1;
      // ds_read quadrant fragments (tile T; landed: steady-state ledger ok)
      f16x8 a[4];
#pragma unroll
      for (int mi = 0; mi < 4; mi++)
        a[mi] = *(const f16x8*)(Ab + ks * 16384 + baseA + (mh * 4 + mi) * 1024);
      if (mh == 0) {
#pragma unroll
        for (int ni = 0; ni < 4; ni++)
          b[ni] = *(const f16x8*)(Ab + ks * 16384 + baseB + ni * 1024);
      }
      // stage one quarter of tile T+1
      if (T + 1 < 16) STAGEQ(T + 1, buf ^ 1, q);
      asm volatile("s_waitcnt vmcnt(4)" ::: "memory");
      __builtin_amdgcn_s_barrier();
      __builtin_amdgcn_s_setprio(1);
#pragma unroll
      for (int mi = 0; mi < 4; mi++)
#pragma unroll
        for (int ni = 0; ni < 4; ni++)
          acc[mh * 4 + mi][ni] =
              __builtin_amdgcn_mfma_f32_16x16x32_f16(a[mi], b[ni], acc[mh * 4 + mi][ni], 0, 0, 0);
      __builtin_amdgcn_s_setprio(0);
      __builtin_amdgcn_s_barrier();
    }
  }
#undef STAGEQ
  asm volatile("s_waitcnt vmcnt(0)" ::: "memory");
  __builtin_amdgcn_s_barrier();

  if (!OUT_I) {
    float* Y = (float*)Yout;
#pragma unroll
    for (int mi = 0; mi < 8; mi++)
#pragma unroll
      for (int j = 0; j < 4; j++) {
        int row = bm0 + wm * 128 + mi * 16 + g * 4 + j;
        if (row < R) {
#pragma unroll
          for (int ni = 0; ni < 4; ni++) {
            float v = acc[mi][ni][j];
            v = (v >= 0.f) ? v : 0.01f * v;
            Y[(size_t)row * 512 + bn0 + wn * 64 + ni * 16 + r16] = v;
          }
        }
      }
  } else {
    // 2 sections of 128 rows; stg = [128][256] f32 = 128KB
    float* stg = (float*)smem;
    const int hc = tid & 63;       // 16B chunk within 256-col row
    const int rg = tid >> 6;       // 8 row groups
#pragma unroll
    for (int h = 0; h < 2; h++) {
      __syncthreads();
      if (wm == h) {
#pragma unroll
        for (int mi = 0; mi < 8; mi++)
#pragma unroll
          for (int j = 0; j < 4; j++) {
            int rl = mi * 16 + g * 4 + j;
#pragma unroll
            for (int ni = 0; ni < 4; ni++) {
              float v = acc[mi][ni][j];
              v = (v >= 0.f) ? v : 0.01f * v;
              stg[rl * 256 + wn * 64 + ni * 16 + r16] = v;
            }
          }
      }
      __syncthreads();
#pragma unroll
      for (int it = 0; it < 16; it++) {
        int rl = rg + it * 8;
        int grow = bm0 + h * 128 + rl;
        if (grow < R) {
          float4 v = *(const float4*)&stg[rl * 256 + hc * 4];
          unsigned short h0 = f2h(v.x), h1 = f2h(v.y), h2 = f2h(v.z), h3 = f2h(v.w);
          uint2 pk;
          pk.x = (unsigned)h0 | ((unsigned)h1 << 16);
          pk.y = (unsigned)h2 | ((unsigned)h3 << 16);
          int oct = (bn0 >> 3) + (hc >> 1);
          *(uint2*)((char*)Yout + (size_t)grow * 1024 + octA(grow, oct) + (hc & 1) * 8) = pk;
        }
      }
    }
  }
}

// colmax reduce stage 1: PPAN rows -> 5 segment rows (1024 cols: [p|r])
__global__ __launch_bounds__(256) void colmax_red1_k(const float* __restrict__ part,
                                                     float* __restrict__ part2) {
  int bx = blockIdx.x;
  int seg = bx >> 2;
  int idx = (bx & 3) * 256 + threadIdx.x;
  int c = idx & 511;
  const float* P = part + (size_t)(idx >> 9) * (PPAN * 512) + c;
  int b0 = seg * 125, b1 = b0 + 125;
  float v = -1e30f;
#pragma unroll 1
  for (int b = b0; b < b1; b += 5) {
    float v0 = P[(size_t)(b + 0) * 512], v1 = P[(size_t)(b + 1) * 512];
    float v2 = P[(size_t)(b + 2) * 512], v3 = P[(size_t)(b + 3) * 512];
    float v4 = P[(size_t)(b + 4) * 512];
    v = fmaxf(v, fmaxf(fmaxf(v0, v1), fmaxf(fmaxf(v2, v3), v4)));
  }
  part2[(size_t)seg * 1024 + idx] = v;
}

// colmax reduce stage 2: 5 segment rows -> m = [mp[512] | mr[512]]
__global__ __launch_bounds__(256) void colmax_red2_k(const float* __restrict__ part2,
                                                     float* __restrict__ m) {
  int idx = blockIdx.x * 256 + threadIdx.x;
  float v = part2[idx];
#pragma unroll
  for (int s = 1; s < 5; s++) v = fmaxf(v, part2[(size_t)s * 1024 + idx]);
  m[idx] = v;
}

// ---------------------------------------------------------------------------
// aggblend: per node n (one wave); depth-2 pipeline (3 slots).
// ---------------------------------------------------------------------------
__global__ __launch_bounds__(256) void aggblend_k(const char* __restrict__ EaH,
                                                  const char* __restrict__ NaH,
                                                  const char* __restrict__ exI,
                                                  const char* __restrict__ nxI,
                                                  const int* __restrict__ src,
                                                  const int* __restrict__ off,
                                                  const int* __restrict__ eid,
                                                  const float* __restrict__ mp,
                                                  const float* __restrict__ mr,
                                                  char* __restrict__ blendH,
                                                  char* __restrict__ z2I) {
  const int w = threadIdx.x >> 6, o = threadIdx.x & 63;
  int n = blockIdx.x * 4 + w;
  if (n >= NNODES) return;
  float m_p[8], m_r[8], nd[8], xd[8], z[8], z2[8];
#pragma unroll
  for (int j = 0; j < 8; j++) {
    m_p[j] = mp[o * 8 + j];
    m_r[j] = mr[o * 8 + j];
    z[j] = 0.f; z2[j] = 0.f;
  }
  {
    unsigned short hn[8], hx[8];
    unpack8(*(const uint4*)(NaH + (size_t)n * 1024 + octA(n, o)), hn);
    unpack8(*(const uint4*)(nxI + (size_t)n * 1024 + octA(n, o)), hx);
#pragma unroll
    for (int j = 0; j < 8; j++) { nd[j] = h2f(hn[j]); xd[j] = h2f(hx[j]); }
  }
  const int i0 = off[n], i1 = off[n + 1];
  const int cnt = i1 - i0;
  if (cnt > 0) {
#define LOADE(ii, e_, ea_, x_, nn_, sv_)                             \
    {                                                                \
      e_ = eid[ii];                                                  \
      int s_ = src[e_];                                              \
      ea_ = *(const uint4*)(EaH + (size_t)e_ * 1024 + octA(e_, o));  \
      x_  = *(const uint4*)(exI + (size_t)e_ * 1024 + octA(e_, o));  \
      nn_ = *(const uint4*)(nxI + (size_t)s_ * 1024 + octA(s_, o));  \
      sv_ = *(const uint4*)(NaH + (size_t)s_ * 1024 + octA(s_, o));  \
    }
    int eA, eB;
    uint4 eaA, xA, nA, svA, eaB, xB, nB, svB;
    LOADE(i0, eA, eaA, xA, nA, svA);
    if (cnt > 1) {
      LOADE(i0 + 1, eB, eaB, xB, nB, svB);
    } else {
      eB = eA; eaB = eaA; xB = xA; nB = nA; svB = svA;
    }
    for (int i = i0; i < i1; ++i) {
      int eC = eB;
      uint4 eaC = eaB, xC = xB, nC = nB, svC = svB;
      if (i + 2 < i1) {
        LOADE(i + 2, eC, eaC, xC, nC, svC);
      }
      unsigned short eh[8], xh[8], sh[8], sn[8];
      unpack8(eaA, eh);
      unpack8(xA, xh);
      unpack8(nA, sh);
      unpack8(svA, sn);
      unsigned short bh[8];
#pragma unroll
      for (int j = 0; j < 8; j++) {
        float ev = h2f(eh[j]);
        float spv = ev + nd[j] - m_p[j];
        float srv = ev + h2f(sn[j]) - m_r[j];
        float ap = __expf(spv);
        float xe = h2f(xh[j]);
        z[j] += ap;
        z2[j] += ap * xe;
        float u = srv - spv;
        float evx = __expf(-fabsf(u));
        float wpos = 1.f / (1.f + evx);
        float wr = (u >= 0.f) ? wpos : 1.f - wpos;
        float xs_ = h2f(sh[j]);
        bh[j] = f2h(wr * xs_ + (1.f - wr) * xd[j]);
      }
      *(uint4*)(blendH + (size_t)eA * 1024 + octA(eA, o)) = pack8(bh);
      eA = eB; eaA = eaB; xA = xB; nA = nB; svA = svB;
      eB = eC; eaB = eaC; xB = xC; nB = nC; svB = svC;
    }
#undef LOADE
  }
  unsigned short zh[8];
#pragma unroll
  for (int j = 0; j < 8; j++) zh[j] = f2h(z2[j] / (z[j] + EPS));
  *(uint4*)(z2I + (size_t)n * 1024 + octA(n, o)) = pack8(zh);
}

// node_conf = nx @ Wnc ([512,55])
__global__ __launch_bounds__(256) void nodeconf_k(const float* __restrict__ nx,
                                                  const float* __restrict__ Wnc,
                                                  float* __restrict__ out) {
  int w = threadIdx.x >> 6, lane = threadIdx.x & 63;
  int n = blockIdx.x * 4 + w;
  const float* r = nx + (size_t)n * D;
  if (lane < 55) {
    float acc = 0.f;
    for (int k = 0; k < D; k++) acc = fmaf(r[k], Wnc[k * 55 + lane], acc);
    out[(size_t)n * 55 + lane] = acc;
  }
}

// edge_conf = ex @ Wec ([512,2]) — float4-vectorized
__global__ __launch_bounds__(256) void edgeconf_k(const float* __restrict__ ex,
                                                  const float* __restrict__ Wec,
                                                  float* __restrict__ out) {
  int w = threadIdx.x >> 6, lane = threadIdx.x & 63;
  int e = blockIdx.x * 4 + w;
  const float* r = ex + (size_t)e * D + lane * 8;
  float4 v0 = *(const float4*)r;
  float4 v1 = *(const float4*)(r + 4);
  const float* wp = Wec + lane * 16;
  float vv[8] = {v0.x, v0.y, v0.z, v0.w, v1.x, v1.y, v1.z, v1.w};
  float a0 = 0.f, a1 = 0.f;
#pragma unroll
  for (int j = 0; j < 8; j++) {
    a0 = fmaf(vv[j], wp[j * 2 + 0], a0);
    a1 = fmaf(vv[j], wp[j * 2 + 1], a1);
  }
#pragma unroll
  for (int off = 32; off; off >>= 1) {
    a0 += __shfl_down(a0, off);
    a1 += __shfl_down(a1, off);
  }
  if (lane == 0) { out[(size_t)e * 2 + 0] = a0; out[(size_t)e * 2 + 1] = a1; }
}

extern "C" void kernel_launch(void* const* d_in, const int* in_sizes, int n_in,
                              void* d_out, int out_size, void* d_ws, size_t ws_size,
                              hipStream_t stream) {
  const float* in_nx = (const float*)d_in[0];
  const float* in_ex = (const float*)d_in[1];
  const int* src = (const int*)d_in[2];
  const int* dst = (const int*)d_in[3];
  const float* Wa = (const float*)d_in[4];
  const float* Wn = (const float*)d_in[5];
  const float* We = (const float*)d_in[6];
  const float* Wnc = (const float*)d_in[7];
  const float* Wec = (const float*)d_in[8];

  float* out = (float*)d_out;
  float* o_nx = out;
  float* o_nc = o_nx + (size_t)NNODES * D;
  float* o_ex = o_nc + (size_t)NNODES * 55;
  float* o_ec = o_ex + (size_t)NEDGES * D;

  const size_t SZ_EH = (size_t)NEDGES * 1024;
  const size_t SZ_NH = (size_t)NNODES * 1024;
  const size_t MATSZ = (size_t)512 * 2048;
  char* w = (char*)d_ws;
  char* EaH = w;
  char* blendH = w + SZ_EH;
  char* exA = w + 2 * SZ_EH;
  char* nxA = w + 3 * SZ_EH;
  char* NaH = w + 3 * SZ_EH + SZ_NH;
  char* z2I = w + 3 * SZ_EH + 2 * SZ_NH;
  float* mpf = (float*)(w + 3 * SZ_EH + 3 * SZ_NH);
  char* WT = w + 3 * SZ_EH + 3 * SZ_NH + 8192;
  char* csr = WT + 15 * MATSZ;
  int* cnt = (int*)csr;
  int* offp = cnt + NNODES + 8;
  int* cur = offp + NNODES + 8;
  int* eid = cur + NNODES + 8;
  float* part_p = (float*)(eid + NEDGES);
  float* part_r = part_p + PPAN * 512;
  float* part2 = part_r + PPAN * 512;

  char* exB = (char*)o_ex;
  char* nxB = (char*)o_nx;

  // one-time prep
  wprep_k<<<dim3(8, 16, 15), 256, 0, stream>>>(Wa, Wn, We, WT);
  toF16_k<<<2048, 256, 0, stream>>>(in_ex, exA, NEDGES * 64);
  toF16_k<<<2048, 256, 0, stream>>>(in_nx, nxA, NNODES * 64);
  hipMemsetAsync(cnt, 0, NNODES * sizeof(int), stream);
  hist_k<<<(NEDGES + 255) / 256, 256, 0, stream>>>(dst, cnt);
  scan_k<<<1, 256, 0, stream>>>(cnt, offp, cur);
  scatter_k<<<(NEDGES + 255) / 256, 256, 0, stream>>>(dst, cur, eid);

  dim3 gE128(4, PPAN);
  dim3 gN(4, (NNODES + 127) / 128);
  dim3 g8(2, 313);

  for (int l = 0; l < LAYERS; l++) {
    const char* WaT = WT + (size_t)l * MATSZ;
    const char* WnT = WT + (size_t)(5 + l) * MATSZ;
    const char* WeT = WT + (size_t)(10 + l) * MATSZ;
    char* exCur = (l & 1) ? exB : exA;
    char* exNxt = (l & 1) ? exA : exB;
    char* nxCur = (l & 1) ? nxB : nxA;
    char* nxNxt = (l & 1) ? nxA : nxB;

    gemmI<512, false, true, false, 128><<<gN, 256, 0, stream>>>(
        nxCur, nullptr, WaT, 64, NaH, NNODES, nullptr, nullptr, nullptr, nullptr, nullptr);
    gemmI<512, false, true, true, 128><<<gE128, 256, 0, stream>>>(
        exCur, nullptr, WaT, 0, EaH, NEDGES, src, dst, NaH, part_p, part_r);

    colmax_red1_k<<<20, 256, 0, stream>>>(part_p, part2);
    colmax_red2_k<<<4, 256, 0, stream>>>(part2, mpf);

    aggblend_k<<<(NNODES + 3) / 4, 256, 0, stream>>>(EaH, NaH, exCur, nxCur, src,
                                                     offp, eid, mpf, mpf + 512, blendH, z2I);

    // node update (ring BM=128)
    if (l < 4)
      gemmI<1024, true, true, false, 128><<<gN, 256, 0, stream>>>(
          z2I, nxCur, WnT, 0, nxNxt, NNODES, nullptr, nullptr, nullptr, nullptr, nullptr);
    else
      gemmI<1024, true, false, false, 128><<<gN, 256, 0, stream>>>(
          z2I, nxCur, WnT, 0, o_nx, NNODES, nullptr, nullptr, nullptr, nullptr, nullptr);

    // edge update: 8-phase 256x256
    if (l < 4)
      gemm8_k<true><<<g8, 512, 0, stream>>>(blendH, exCur, WeT, exNxt);
    else
      gemm8_k<false><<<g8, 512, 0, stream>>>(blendH, exCur, WeT, o_ex);
  }

  nodeconf_k<<<NNODES / 4, 256, 0, stream>>>(o_nx, Wnc, o_nc);
  edgeconf_k<<<NEDGES / 4, 256, 0, stream>>>(o_ex, Wec, o_ec);
}

// Round 17
// 1877.194 us; speedup vs baseline: 1.1048x; 1.0949x over previous
//
#include <hip/hip_runtime.h>
#include <hip/hip_fp16.h>
#include <math.h>

#define D 512
#define NNODES 10000
#define NEDGES 80000
#define LAYERS 5
#define EPS 1e-5f
#define PPAN 625   // edge M-panels at BM=128 (CMAX producer)

typedef _Float16 f16x8 __attribute__((ext_vector_type(8)));
typedef float f32x4 __attribute__((ext_vector_type(4)));

// ---------- fp16 helpers ----------
__device__ inline unsigned short f2h(float x) { return __half_as_ushort(__float2half(x)); }
__device__ inline float h2f(unsigned short u) { return __half2float(__ushort_as_half(u)); }
__device__ inline uint4 pack8(const unsigned short* v) {
  uint4 r;
  r.x = (unsigned)v[0] | ((unsigned)v[1] << 16);
  r.y = (unsigned)v[2] | ((unsigned)v[3] << 16);
  r.z = (unsigned)v[4] | ((unsigned)v[5] << 16);
  r.w = (unsigned)v[6] | ((unsigned)v[7] << 16);
  return r;
}
__device__ inline void unpack8(uint4 v, unsigned short* o) {
  o[0] = v.x & 0xffff; o[1] = v.x >> 16;
  o[2] = v.y & 0xffff; o[3] = v.y >> 16;
  o[4] = v.z & 0xffff; o[5] = v.z >> 16;
  o[6] = v.w & 0xffff; o[7] = v.w >> 16;
}

__device__ inline void gload16(const void* g, void* l) {
  __builtin_amdgcn_global_load_lds((const __attribute__((address_space(1))) void*)g,
                                   (__attribute__((address_space(3))) void*)l, 16, 0, 0);
}

// ---------------------------------------------------------------------------
// A-format (activations AND hi-only weights): fp16 rows; activation row =
// 1024 B (K=512), weight row = 2048 B (K=1024). Within each 64 B K-block
// (4 octets of 16 B), octet o sits at slot (o&3)^((r>>1)&3).
// ---------------------------------------------------------------------------
__device__ inline int octA(int r, int o) {
  return ((o >> 2) << 6) + ((((o & 3) ^ ((r >> 1) & 3))) << 4);
}

// f32 [R][512] -> A-format fp16
__global__ __launch_bounds__(256) void toF16_k(const float* __restrict__ src,
                                               char* __restrict__ dst, int nOct) {
  for (long long i = (long long)blockIdx.x * 256 + threadIdx.x; i < nOct;
       i += (long long)gridDim.x * 256) {
    int row = (int)(i >> 6), oct = (int)(i & 63);
    const float* s = src + (size_t)row * 512 + oct * 8;
    float4 x0 = *(const float4*)s, x1 = *(const float4*)(s + 4);
    float xs[8] = {x0.x, x0.y, x0.z, x0.w, x1.x, x1.y, x1.z, x1.w};
    unsigned short h[8];
#pragma unroll
    for (int j = 0; j < 8; j++) h[j] = f2h(xs[j]);
    *(uint4*)(dst + (size_t)row * 1024 + octA(row, oct)) = pack8(h);
  }
}

// weight prep: W[1024][512] f32 (15 mats) -> WT[n=512][k=1024] hi-only fp16
__global__ __launch_bounds__(256) void wprep_k(const float* __restrict__ Wa,
                                               const float* __restrict__ Wn,
                                               const float* __restrict__ We,
                                               char* __restrict__ WT) {
  __shared__ float tile[64][65];
  int mat = blockIdx.z;
  const float* W = (mat < 5) ? Wa + (size_t)mat * 1024 * 512
                 : (mat < 10) ? Wn + (size_t)(mat - 5) * 1024 * 512
                              : We + (size_t)(mat - 10) * 1024 * 512;
  char* out = WT + (size_t)mat * 512 * 2048;
  int n0 = blockIdx.x * 64, k0 = blockIdx.y * 64;
  int t = threadIdx.x;
  int ty = t >> 2, tx = t & 3;
  const float* wr = W + (size_t)(k0 + ty) * 512 + n0 + tx * 16;
  float4 v0 = *(const float4*)(wr + 0), v1 = *(const float4*)(wr + 4);
  float4 v2 = *(const float4*)(wr + 8), v3 = *(const float4*)(wr + 12);
  float vv[16] = {v0.x, v0.y, v0.z, v0.w, v1.x, v1.y, v1.z, v1.w,
                  v2.x, v2.y, v2.z, v2.w, v3.x, v3.y, v3.z, v3.w};
#pragma unroll
  for (int j = 0; j < 16; j++) tile[ty][tx * 16 + j] = vv[j];
  __syncthreads();
#pragma unroll
  for (int p = 0; p < 2; p++) {
    int chunk = t + p * 256;
    int n = chunk >> 3, cc = chunk & 7;
    float xs[8];
#pragma unroll
    for (int j = 0; j < 8; j++) xs[j] = tile[cc * 8 + j][n];
    unsigned short h[8];
#pragma unroll
    for (int j = 0; j < 8; j++) h[j] = f2h(xs[j]);
    int ng = n0 + n;
    int kc = (k0 >> 3) + cc;   // octet index 0..127
    *(uint4*)(out + (size_t)ng * 2048 + octA(ng, kc)) = pack8(h);
  }
}

// ---------------------------------------------------------------------------
// CSR build over dst (dst fixed across layers)
// ---------------------------------------------------------------------------
__global__ __launch_bounds__(256) void hist_k(const int* __restrict__ dst, int* __restrict__ cnt) {
  int e = blockIdx.x * 256 + threadIdx.x;
  if (e < NEDGES) atomicAdd(&cnt[dst[e]], 1);
}

__global__ __launch_bounds__(256) void scan_k(const int* __restrict__ cnt,
                                              int* __restrict__ off, int* __restrict__ cur) {
  __shared__ int part[256];
  const int CH = (NNODES + 255) / 256;
  int t = threadIdx.x;
  int s = 0;
  int l0 = t * CH;
  for (int i = 0; i < CH; i++) {
    int idx = l0 + i;
    if (idx < NNODES) s += cnt[idx];
  }
  part[t] = s;
  __syncthreads();
  if (t == 0) {
    int acc = 0;
    for (int i = 0; i < 256; i++) { int v = part[i]; part[i] = acc; acc += v; }
  }
  __syncthreads();
  int acc = part[t];
  for (int i = 0; i < CH; i++) {
    int idx = l0 + i;
    if (idx < NNODES) { off[idx] = acc; cur[idx] = acc; acc += cnt[idx]; }
  }
  if (t == 255) off[NNODES] = acc;
}

__global__ __launch_bounds__(256) void scatter_k(const int* __restrict__ dst,
                                                 int* __restrict__ cur, int* __restrict__ eid) {
  int e = blockIdx.x * 256 + threadIdx.x;
  if (e < NEDGES) {
    int p = atomicAdd(&cur[dst[e]], 1);
    eid[p] = e;
  }
}

// ---------------------------------------------------------------------------
// gemmI (ring-3): fp16 x fp16-hi, counted vmcnt + raw s_barrier, setprio.
// BM = 128 (4 waves) or 256 (8 waves). OUT_I epilogue: 32B-chunk layout —
// one uint4 A-format store per thread-iter; CMAX: one uint4 NaH gather per
// endpoint (8 cols/thread).
// ---------------------------------------------------------------------------
template<int KT, bool ACT, bool OUT_I, bool CMAX, int BM>
__global__ __launch_bounds__(BM * 2) void gemmI(const char* __restrict__ X1,
                                                const char* __restrict__ X2,
                                                const char* __restrict__ BW, int cb0,
                                                void* __restrict__ Yout, int R,
                                                const int* __restrict__ srcI,
                                                const int* __restrict__ dstI,
                                                const char* __restrict__ NaH,
                                                float* __restrict__ part_p,
                                                float* __restrict__ part_r) {
  constexpr int T = BM * 2;
  constexpr int BUF = (BM == 256) ? 24576 : 16384;
  constexpr int BOFF = (BM == 256) ? 16384 : 8192;
  constexpr int NH = BM / 64;
  constexpr int G = T / 16;                 // 32B-chunk row groups
  __shared__ char smem[3 * BUF];
  const int tid = threadIdx.x;
  const int lane = tid & 63, wv = tid >> 6;
  const int NT = KT / 32;
  int flat = blockIdx.y * 4 + blockIdx.x;
  int total = gridDim.y * 4;
  int xcd = flat & 7, idx = flat >> 3;
  int q = total >> 3, rem = total & 7;
  int base = xcd * q + (xcd < rem ? xcd : rem);
  int f2 = base + idx;
  const int bn0 = (f2 & 3) * 128, bm0 = (f2 >> 2) * BM;
  const int r16 = lane & 15, g = lane >> 4;
  const int mo = (wv >> 1) * 64, no = (wv & 1) * 64;
  const int lr16 = lane >> 2, ls16 = (lane & 3) * 16;
  f32x4 acc[4][4];
#pragma unroll
  for (int i = 0; i < 4; i++)
#pragma unroll
    for (int j = 0; j < 4; j++) acc[i][j] = (f32x4){0.f, 0.f, 0.f, 0.f};

  int offA[4], offB[4];
#pragma unroll
  for (int mi = 0; mi < 4; mi++) {
    int row = mo + mi * 16 + r16;
    offA[mi] = row * 64 + ((g ^ ((row >> 1) & 3)) << 4);
  }
#pragma unroll
  for (int ni = 0; ni < 4; ni++) {
    int row = no + ni * 16 + r16;
    offB[ni] = BOFF + row * 64 + ((g ^ ((row >> 1) & 3)) << 4);
  }

  const char* pA0;
  const char* pA1;
  const char* pB0;
  const char* pB1;
  {
    int g0 = bm0 + wv * 16 + lr16; if (g0 > R - 1) g0 = R - 1;
    int g1 = bm0 + (BM / 2) + wv * 16 + lr16; if (g1 > R - 1) g1 = R - 1;
    pA0 = X1 + (size_t)g0 * 1024 + ls16;
    pA1 = X1 + (size_t)g1 * 1024 + ls16;
    int n0r = bn0 + wv * 16 + lr16;
    pB0 = BW + (size_t)n0r * 2048 + cb0 * 16 + ls16;
    if (BM == 128) {
      int n1r = bn0 + (4 + wv) * 16 + lr16;
      pB1 = BW + (size_t)n1r * 2048 + cb0 * 16 + ls16;
    } else {
      pB1 = pB0;
    }
  }

  int us = 0;
#define STAGE()                                                 \
  {                                                             \
    char* sb = smem + (us % 3) * BUF;                           \
    gload16(pA0, sb + wv * 1024);                               \
    gload16(pA1, sb + ((BM / 32) + wv) * 1024);                 \
    gload16(pB0, sb + BOFF + wv * 1024);                        \
    if (BM == 128) gload16(pB1, sb + BOFF + (4 + wv) * 1024);   \
    pA0 += 64; pA1 += 64; pB0 += 64;                            \
    if (BM == 128) pB1 += 64;                                   \
    us++;                                                       \
  }

  STAGE();
  STAGE();
  for (int t = 0; t < NT; ++t) {
    if (t + 1 < NT) {
      if (BM == 128) asm volatile("s_waitcnt vmcnt(4)" ::: "memory");
      else           asm volatile("s_waitcnt vmcnt(3)" ::: "memory");
    } else {
      asm volatile("s_waitcnt vmcnt(0)" ::: "memory");
    }
    __builtin_amdgcn_s_barrier();
    if (us < NT) {
      if (KT == 1024 && us == 16) {
        int g0 = bm0 + wv * 16 + lr16; if (g0 > R - 1) g0 = R - 1;
        int g1 = bm0 + (BM / 2) + wv * 16 + lr16; if (g1 > R - 1) g1 = R - 1;
        pA0 = X2 + (size_t)g0 * 1024 + ls16;
        pA1 = X2 + (size_t)g1 * 1024 + ls16;
      }
      STAGE();
    }
    const char* As = smem + (t % 3) * BUF;
    f16x8 a[4], b[4];
#pragma unroll
    for (int mi = 0; mi < 4; mi++) a[mi] = *(const f16x8*)(As + offA[mi]);
#pragma unroll
    for (int ni = 0; ni < 4; ni++) b[ni] = *(const f16x8*)(As + offB[ni]);
    __builtin_amdgcn_s_setprio(1);
#pragma unroll
    for (int mi = 0; mi < 4; mi++)
#pragma unroll
      for (int ni = 0; ni < 4; ni++)
        acc[mi][ni] = __builtin_amdgcn_mfma_f32_16x16x32_f16(a[mi], b[ni], acc[mi][ni], 0, 0, 0);
    __builtin_amdgcn_s_setprio(0);
  }
#undef STAGE

  if (!OUT_I) {
    float* Y = (float*)Yout;
#pragma unroll
    for (int mi = 0; mi < 4; mi++)
#pragma unroll
      for (int j = 0; j < 4; j++) {
        int row = bm0 + mo + mi * 16 + g * 4 + j;
        if (row < R) {
#pragma unroll
          for (int ni = 0; ni < 4; ni++) {
            float v = acc[mi][ni][j];
            if (ACT) v = (v >= 0.f) ? v : 0.01f * v;
            Y[(size_t)row * 512 + bn0 + no + ni * 16 + r16] = v;
          }
        }
      }
  } else {
    // 32B-chunk epilogue: thread owns one output octet (8 cols) per iter.
    float* stg = (float*)smem;
    const int hc = tid & 15;                // chunk 0..15 within 128-col panel
    const int rg = tid >> 4;                // row in group (G rows per pass)
    const int oct = (bn0 >> 3) + hc;        // A-format octet index
    float mp8[8], mr8[8];
#pragma unroll
    for (int j = 0; j < 8; j++) { mp8[j] = -1e30f; mr8[j] = -1e30f; }
#pragma unroll
    for (int h = 0; h < NH; h++) {
      __syncthreads();
      if ((wv >> 1) == h) {
#pragma unroll
        for (int mi = 0; mi < 4; mi++)
#pragma unroll
          for (int j = 0; j < 4; j++) {
            int rl = mi * 16 + g * 4 + j;
#pragma unroll
            for (int ni = 0; ni < 4; ni++) {
              float v = acc[mi][ni][j];
              if (ACT) v = (v >= 0.f) ? v : 0.01f * v;
              stg[rl * 128 + no + ni * 16 + r16] = v;
            }
          }
      }
      __syncthreads();
#pragma unroll
      for (int qq = 0; qq < 1024 / T; qq++) {
        int rl = rg + qq * G;
        int grow = bm0 + h * 64 + rl;
        if (grow < R) {
          float4 v0 = *(const float4*)&stg[rl * 128 + hc * 8];
          float4 v1 = *(const float4*)&stg[rl * 128 + hc * 8 + 4];
          float vs[8] = {v0.x, v0.y, v0.z, v0.w, v1.x, v1.y, v1.z, v1.w};
          unsigned short hh[8];
#pragma unroll
          for (int j = 0; j < 8; j++) hh[j] = f2h(vs[j]);
          *(uint4*)((char*)Yout + (size_t)grow * 1024 + octA(grow, oct)) = pack8(hh);
          if (CMAX) {
            int d = dstI[grow], s = srcI[grow];
            uint4 hd = *(const uint4*)(NaH + (size_t)d * 1024 + octA(d, oct));
            uint4 hs = *(const uint4*)(NaH + (size_t)s * 1024 + octA(s, oct));
            unsigned short dh[8], sh[8];
            unpack8(hd, dh);
            unpack8(hs, sh);
#pragma unroll
            for (int j = 0; j < 8; j++) {
              float qv = h2f(hh[j]);
              mp8[j] = fmaxf(mp8[j], qv + h2f(dh[j]));
              mr8[j] = fmaxf(mr8[j], qv + h2f(sh[j]));
            }
          }
        }
      }
    }
    if (CMAX) {
      __syncthreads();
      float* red = (float*)smem;  // [G][128] p, then [G][128] r
#pragma unroll
      for (int j = 0; j < 8; j++) {
        red[rg * 128 + hc * 8 + j] = mp8[j];
        red[G * 128 + rg * 128 + hc * 8 + j] = mr8[j];
      }
      __syncthreads();
      if (tid < 128) {
        float vp = -1e30f, vr = -1e30f;
#pragma unroll
        for (int gi = 0; gi < G; gi++) {
          vp = fmaxf(vp, red[gi * 128 + tid]);
          vr = fmaxf(vr, red[G * 128 + gi * 128 + tid]);
        }
        int panel = f2 >> 2;
        part_p[(size_t)panel * 512 + bn0 + tid] = vp;
        part_r[(size_t)panel * 512 + bn0 + tid] = vr;
      }
    }
  }
}

// colmax reduce stage 1: PPAN rows -> 5 segment rows (1024 cols: [p|r])
__global__ __launch_bounds__(256) void colmax_red1_k(const float* __restrict__ part,
                                                     float* __restrict__ part2) {
  int bx = blockIdx.x;
  int seg = bx >> 2;
  int idx = (bx & 3) * 256 + threadIdx.x;
  int c = idx & 511;
  const float* P = part + (size_t)(idx >> 9) * (PPAN * 512) + c;
  int b0 = seg * 125, b1 = b0 + 125;
  float v = -1e30f;
#pragma unroll 1
  for (int b = b0; b < b1; b += 5) {
    float v0 = P[(size_t)(b + 0) * 512], v1 = P[(size_t)(b + 1) * 512];
    float v2 = P[(size_t)(b + 2) * 512], v3 = P[(size_t)(b + 3) * 512];
    float v4 = P[(size_t)(b + 4) * 512];
    v = fmaxf(v, fmaxf(fmaxf(v0, v1), fmaxf(fmaxf(v2, v3), v4)));
  }
  part2[(size_t)seg * 1024 + idx] = v;
}

// colmax reduce stage 2: 5 segment rows -> m = [mp[512] | mr[512]]
__global__ __launch_bounds__(256) void colmax_red2_k(const float* __restrict__ part2,
                                                     float* __restrict__ m) {
  int idx = blockIdx.x * 256 + threadIdx.x;
  float v = part2[idx];
#pragma unroll
  for (int s = 1; s < 5; s++) v = fmaxf(v, part2[(size_t)s * 1024 + idx]);
  m[idx] = v;
}

// ---------------------------------------------------------------------------
// aggblend: per node n (one wave); depth-2 pipeline (3 slots).
// ---------------------------------------------------------------------------
__global__ __launch_bounds__(256) void aggblend_k(const char* __restrict__ EaH,
                                                  const char* __restrict__ NaH,
                                                  const char* __restrict__ exI,
                                                  const char* __restrict__ nxI,
                                                  const int* __restrict__ src,
                                                  const int* __restrict__ off,
                                                  const int* __restrict__ eid,
                                                  const float* __restrict__ mp,
                                                  const float* __restrict__ mr,
                                                  char* __restrict__ blendH,
                                                  char* __restrict__ z2I) {
  const int w = threadIdx.x >> 6, o = threadIdx.x & 63;
  int n = blockIdx.x * 4 + w;
  if (n >= NNODES) return;
  float m_p[8], m_r[8], nd[8], xd[8], z[8], z2[8];
#pragma unroll
  for (int j = 0; j < 8; j++) {
    m_p[j] = mp[o * 8 + j];
    m_r[j] = mr[o * 8 + j];
    z[j] = 0.f; z2[j] = 0.f;
  }
  {
    unsigned short hn[8], hx[8];
    unpack8(*(const uint4*)(NaH + (size_t)n * 1024 + octA(n, o)), hn);
    unpack8(*(const uint4*)(nxI + (size_t)n * 1024 + octA(n, o)), hx);
#pragma unroll
    for (int j = 0; j < 8; j++) { nd[j] = h2f(hn[j]); xd[j] = h2f(hx[j]); }
  }
  const int i0 = off[n], i1 = off[n + 1];
  const int cnt = i1 - i0;
  if (cnt > 0) {
#define LOADE(ii, e_, ea_, x_, nn_, sv_)                             \
    {                                                                \
      e_ = eid[ii];                                                  \
      int s_ = src[e_];                                              \
      ea_ = *(const uint4*)(EaH + (size_t)e_ * 1024 + octA(e_, o));  \
      x_  = *(const uint4*)(exI + (size_t)e_ * 1024 + octA(e_, o));  \
      nn_ = *(const uint4*)(nxI + (size_t)s_ * 1024 + octA(s_, o));  \
      sv_ = *(const uint4*)(NaH + (size_t)s_ * 1024 + octA(s_, o));  \
    }
    int eA, eB;
    uint4 eaA, xA, nA, svA, eaB, xB, nB, svB;
    LOADE(i0, eA, eaA, xA, nA, svA);
    if (cnt > 1) {
      LOADE(i0 + 1, eB, eaB, xB, nB, svB);
    } else {
      eB = eA; eaB = eaA; xB = xA; nB = nA; svB = svA;
    }
    for (int i = i0; i < i1; ++i) {
      int eC = eB;
      uint4 eaC = eaB, xC = xB, nC = nB, svC = svB;
      if (i + 2 < i1) {
        LOADE(i + 2, eC, eaC, xC, nC, svC);
      }
      unsigned short eh[8], xh[8], sh[8], sn[8];
      unpack8(eaA, eh);
      unpack8(xA, xh);
      unpack8(nA, sh);
      unpack8(svA, sn);
      unsigned short bh[8];
#pragma unroll
      for (int j = 0; j < 8; j++) {
        float ev = h2f(eh[j]);
        float spv = ev + nd[j] - m_p[j];
        float srv = ev + h2f(sn[j]) - m_r[j];
        float ap = __expf(spv);
        float xe = h2f(xh[j]);
        z[j] += ap;
        z2[j] += ap * xe;
        float u = srv - spv;
        float evx = __expf(-fabsf(u));
        float wpos = 1.f / (1.f + evx);
        float wr = (u >= 0.f) ? wpos : 1.f - wpos;
        float xs_ = h2f(sh[j]);
        bh[j] = f2h(wr * xs_ + (1.f - wr) * xd[j]);
      }
      *(uint4*)(blendH + (size_t)eA * 1024 + octA(eA, o)) = pack8(bh);
      eA = eB; eaA = eaB; xA = xB; nA = nB; svA = svB;
      eB = eC; eaB = eaC; xB = xC; nB = nC; svB = svC;
    }
#undef LOADE
  }
  unsigned short zh[8];
#pragma unroll
  for (int j = 0; j < 8; j++) zh[j] = f2h(z2[j] / (z[j] + EPS));
  *(uint4*)(z2I + (size_t)n * 1024 + octA(n, o)) = pack8(zh);
}

// node_conf = nx @ Wnc ([512,55])
__global__ __launch_bounds__(256) void nodeconf_k(const float* __restrict__ nx,
                                                  const float* __restrict__ Wnc,
                                                  float* __restrict__ out) {
  int w = threadIdx.x >> 6, lane = threadIdx.x & 63;
  int n = blockIdx.x * 4 + w;
  const float* r = nx + (size_t)n * D;
  if (lane < 55) {
    float acc = 0.f;
    for (int k = 0; k < D; k++) acc = fmaf(r[k], Wnc[k * 55 + lane], acc);
    out[(size_t)n * 55 + lane] = acc;
  }
}

// edge_conf = ex @ Wec ([512,2]) — float4-vectorized
__global__ __launch_bounds__(256) void edgeconf_k(const float* __restrict__ ex,
                                                  const float* __restrict__ Wec,
                                                  float* __restrict__ out) {
  int w = threadIdx.x >> 6, lane = threadIdx.x & 63;
  int e = blockIdx.x * 4 + w;
  const float* r = ex + (size_t)e * D + lane * 8;
  float4 v0 = *(const float4*)r;
  float4 v1 = *(const float4*)(r + 4);
  const float* wp = Wec + lane * 16;
  float vv[8] = {v0.x, v0.y, v0.z, v0.w, v1.x, v1.y, v1.z, v1.w};
  float a0 = 0.f, a1 = 0.f;
#pragma unroll
  for (int j = 0; j < 8; j++) {
    a0 = fmaf(vv[j], wp[j * 2 + 0], a0);
    a1 = fmaf(vv[j], wp[j * 2 + 1], a1);
  }
#pragma unroll
  for (int off = 32; off; off >>= 1) {
    a0 += __shfl_down(a0, off);
    a1 += __shfl_down(a1, off);
  }
  if (lane == 0) { out[(size_t)e * 2 + 0] = a0; out[(size_t)e * 2 + 1] = a1; }
}

extern "C" void kernel_launch(void* const* d_in, const int* in_sizes, int n_in,
                              void* d_out, int out_size, void* d_ws, size_t ws_size,
                              hipStream_t stream) {
  const float* in_nx = (const float*)d_in[0];
  const float* in_ex = (const float*)d_in[1];
  const int* src = (const int*)d_in[2];
  const int* dst = (const int*)d_in[3];
  const float* Wa = (const float*)d_in[4];
  const float* Wn = (const float*)d_in[5];
  const float* We = (const float*)d_in[6];
  const float* Wnc = (const float*)d_in[7];
  const float* Wec = (const float*)d_in[8];

  float* out = (float*)d_out;
  float* o_nx = out;
  float* o_nc = o_nx + (size_t)NNODES * D;
  float* o_ex = o_nc + (size_t)NNODES * 55;
  float* o_ec = o_ex + (size_t)NEDGES * D;

  const size_t SZ_EH = (size_t)NEDGES * 1024;
  const size_t SZ_NH = (size_t)NNODES * 1024;
  const size_t MATSZ = (size_t)512 * 2048;
  char* w = (char*)d_ws;
  char* EaH = w;
  char* blendH = w + SZ_EH;
  char* exA = w + 2 * SZ_EH;
  char* nxA = w + 3 * SZ_EH;
  char* NaH = w + 3 * SZ_EH + SZ_NH;
  char* z2I = w + 3 * SZ_EH + 2 * SZ_NH;
  float* mpf = (float*)(w + 3 * SZ_EH + 3 * SZ_NH);
  char* WT = w + 3 * SZ_EH + 3 * SZ_NH + 8192;
  char* csr = WT + 15 * MATSZ;
  int* cnt = (int*)csr;
  int* offp = cnt + NNODES + 8;
  int* cur = offp + NNODES + 8;
  int* eid = cur + NNODES + 8;
  float* part_p = (float*)(eid + NEDGES);
  float* part_r = part_p + PPAN * 512;
  float* part2 = part_r + PPAN * 512;

  char* exB = (char*)o_ex;
  char* nxB = (char*)o_nx;

  // one-time prep
  wprep_k<<<dim3(8, 16, 15), 256, 0, stream>>>(Wa, Wn, We, WT);
  toF16_k<<<2048, 256, 0, stream>>>(in_ex, exA, NEDGES * 64);
  toF16_k<<<2048, 256, 0, stream>>>(in_nx, nxA, NNODES * 64);
  hipMemsetAsync(cnt, 0, NNODES * sizeof(int), stream);
  hist_k<<<(NEDGES + 255) / 256, 256, 0, stream>>>(dst, cnt);
  scan_k<<<1, 256, 0, stream>>>(cnt, offp, cur);
  scatter_k<<<(NEDGES + 255) / 256, 256, 0, stream>>>(dst, cur, eid);

  dim3 gE128(4, PPAN);                // (4, 625) BM=128 (Ea+CMAX)
  dim3 gE256(4, 313);                 // (4, 313) BM=256 (edge updates)
  dim3 gN(4, (NNODES + 127) / 128);   // (4, 79)  BM=128

  for (int l = 0; l < LAYERS; l++) {
    const char* WaT = WT + (size_t)l * MATSZ;
    const char* WnT = WT + (size_t)(5 + l) * MATSZ;
    const char* WeT = WT + (size_t)(10 + l) * MATSZ;
    char* exCur = (l & 1) ? exB : exA;
    char* exNxt = (l & 1) ? exA : exB;
    char* nxCur = (l & 1) ? nxB : nxA;
    char* nxNxt = (l & 1) ? nxA : nxB;

    // NaH = fp16(nx @ Wa_bot), then EaH = fp16(ex @ Wa_top) with fused colmax
    gemmI<512, false, true, false, 128><<<gN, 256, 0, stream>>>(
        nxCur, nullptr, WaT, 64, NaH, NNODES, nullptr, nullptr, nullptr, nullptr, nullptr);
    gemmI<512, false, true, true, 128><<<gE128, 256, 0, stream>>>(
        exCur, nullptr, WaT, 0, EaH, NEDGES, src, dst, NaH, part_p, part_r);

    colmax_red1_k<<<20, 256, 0, stream>>>(part_p, part2);
    colmax_red2_k<<<4, 256, 0, stream>>>(part2, mpf);

    aggblend_k<<<(NNODES + 3) / 4, 256, 0, stream>>>(EaH, NaH, exCur, nxCur, src,
                                                     offp, eid, mpf, mpf + 512, blendH, z2I);

    // node update: nx' = act(concat(z2, nx) @ Wn)
    if (l < 4)
      gemmI<1024, true, true, false, 128><<<gN, 256, 0, stream>>>(
          z2I, nxCur, WnT, 0, nxNxt, NNODES, nullptr, nullptr, nullptr, nullptr, nullptr);
    else
      gemmI<1024, true, false, false, 128><<<gN, 256, 0, stream>>>(
          z2I, nxCur, WnT, 0, o_nx, NNODES, nullptr, nullptr, nullptr, nullptr, nullptr);

    // edge update: ex' = act(concat(blend, ex) @ We)  — ring BM=256
    if (l < 4)
      gemmI<1024, true, true, false, 256><<<gE256, 512, 0, stream>>>(
          blendH, exCur, WeT, 0, exNxt, NEDGES, nullptr, nullptr, nullptr, nullptr, nullptr);
    else
      gemmI<1024, true, false, false, 256><<<gE256, 512, 0, stream>>>(
          blendH, exCur, WeT, 0, o_ex, NEDGES, nullptr, nullptr, nullptr, nullptr, nullptr);
  }

  nodeconf_k<<<NNODES / 4, 256, 0, stream>>>(o_nx, Wnc, o_nc);
  edgeconf_k<<<NEDGES / 4, 256, 0, stream>>>(o_ex, Wec, o_ec);
}